// Round 1
// baseline (1487.315 us; speedup 1.0000x reference)
//
#include <hip/hip_runtime.h>
#include <stdint.h>

// TopK SAE forward, MI355X/gfx950.
// bf16-MFMA approximate encoder (fp16 Z scratch) -> register-held single-pass
// candidate select (1024 linear bins, positive-only histogram, margin 0.015)
// -> exact fp64 recompute of ~77 candidates/row -> true top-64 (index
// tie-break) -> fused zero+scatter+sparse-decode with bf16 W_decT.
//
// R1: enc_gemm rewritten as 256x256-tile, BK=32, 8-wave pipeline:
//   quad-buffered LDS (128KB), prefetch distance 3, counted vmcnt(8)
//   (never drains in steady state), XOR-swizzled LDS (conflict-free
//   ds_read_b128 via pre-swizzled global source), setprio around MFMA,
//   bijective XCD-aware block swizzle. K-accumulation chain is bitwise
//   identical to the previous verified kernel.

#define M_BATCH 8192
#define K_DIM   1024
#define N_LAT   16384
#define TOPK    64
#define CAND_CAP 256
#define MARGIN  0.015f

typedef float f32x4 __attribute__((ext_vector_type(4)));
typedef unsigned int u32x4 __attribute__((ext_vector_type(4)));
typedef short s16x8 __attribute__((ext_vector_type(8)));
typedef unsigned short u16x8 __attribute__((ext_vector_type(8)));

typedef __attribute__((address_space(3))) void       lds_void;
typedef const __attribute__((address_space(1))) void glb_void;

__device__ __forceinline__ void async_copy16(const void* g, void* l) {
    __builtin_amdgcn_global_load_lds((glb_void*)g, (lds_void*)l, 16, 0, 0);
}

__device__ __forceinline__ unsigned short f2bf(float f) {
    uint32_t u = __float_as_uint(f);
    uint32_t r = (u + 0x7FFFu + ((u >> 16) & 1u)) >> 16;   // RNE
    return (unsigned short)r;
}
__device__ __forceinline__ float bf2f(unsigned short h) {
    return __uint_as_float(((uint32_t)h) << 16);
}
__device__ __forceinline__ unsigned short f2h(float f) {
    _Float16 h = (_Float16)f;
    unsigned short u;
    __builtin_memcpy(&u, &h, 2);
    return u;
}
__device__ __forceinline__ float h2f(unsigned short u) {
    _Float16 h;
    __builtin_memcpy(&h, &u, 2);
    return (float)h;
}

// ---------------- K0a: fp32 -> bf16 conversion ----------------
__global__ void to_bf16(const float4* __restrict__ src, unsigned short* __restrict__ dst,
                        int nvec) {
    int i = blockIdx.x * blockDim.x + threadIdx.x;
    if (i < nvec) {
        float4 f = src[i];
        ushort4 o;
        o.x = f2bf(f.x); o.y = f2bf(f.y); o.z = f2bf(f.z); o.w = f2bf(f.w);
        *(ushort4*)(dst + (size_t)i * 4) = o;
    }
}

// ---------------- K0b: W_dec [1024,16384] fp32 -> W_decT [16384,1024] bf16 ----------------
__global__ void transpose_wdec(const float* __restrict__ Wd, unsigned short* __restrict__ WdT) {
    __shared__ float tile[64][65];
    int bj = blockIdx.x;
    int bi = blockIdx.y;
    int t = threadIdx.x;
    int tj = t & 63, ti4 = t >> 6;
    #pragma unroll
    for (int rr = 0; rr < 16; rr++) {
        int i = ti4 * 16 + rr;
        tile[i][tj] = Wd[(size_t)(bi * 64 + i) * N_LAT + bj * 64 + tj];
    }
    __syncthreads();
    int ti = t & 63, tj4 = t >> 6;
    #pragma unroll
    for (int rr = 0; rr < 16; rr++) {
        int j = tj4 * 16 + rr;
        WdT[(size_t)(bj * 64 + j) * K_DIM + bi * 64 + ti] = f2bf(tile[ti][j]);
    }
}

// ---------------- K1: bf16 MFMA encoder GEMM, 256x256 tile, pipelined ----------------
// LDS buffer layout (per 32KB buffer): A [256 rows][4 units of 16B], then B same
// at +16384. Unit u of row r stored at u ^ ((r>>1)&3)  (involution; applied by
// pre-swizzling the global source; global_load_lds dest stays linear).
template<bool STAGE>
__device__ __forceinline__ void ktile256(
        const char* smemc, unsigned bufOff,
        unsigned aRowBase, unsigned bRowBase,
        f32x4 (&acc)[8][4],
        const unsigned short* sA0, const unsigned short* sA1,
        const unsigned short* sB0, const unsigned short* sB1,
        char* db)
{
    const char* bufA = smemc + bufOff;
    const char* bufB = bufA + 16384;
    if constexpr (STAGE) {
        async_copy16(sA0, db);
        async_copy16(sB0, db + 16384);
    }
    s16x8 bfr[4], afr[4];
    #pragma unroll
    for (int ni = 0; ni < 4; ni++)
        bfr[ni] = *(const s16x8*)(bufB + bRowBase + ni * 1024);
    #pragma unroll
    for (int mi = 0; mi < 4; mi++)
        afr[mi] = *(const s16x8*)(bufA + aRowBase + mi * 1024);
    __builtin_amdgcn_s_setprio(1);
    #pragma unroll
    for (int mi = 0; mi < 4; mi++)
        #pragma unroll
        for (int ni = 0; ni < 4; ni++)
            acc[mi][ni] = __builtin_amdgcn_mfma_f32_16x16x32_bf16(
                afr[mi], bfr[ni], acc[mi][ni], 0, 0, 0);
    __builtin_amdgcn_s_setprio(0);
    if constexpr (STAGE) {
        async_copy16(sA1, db + 8192);
        async_copy16(sB1, db + 24576);
    }
    #pragma unroll
    for (int mi = 0; mi < 4; mi++)
        afr[mi] = *(const s16x8*)(bufA + aRowBase + (4 + mi) * 1024);
    __builtin_amdgcn_s_setprio(1);
    #pragma unroll
    for (int mi = 0; mi < 4; mi++)
        #pragma unroll
        for (int ni = 0; ni < 4; ni++)
            acc[4 + mi][ni] = __builtin_amdgcn_mfma_f32_16x16x32_bf16(
                afr[mi], bfr[ni], acc[4 + mi][ni], 0, 0, 0);
    __builtin_amdgcn_s_setprio(0);
}

__global__ __launch_bounds__(512, 2) void enc_gemm256(
        const unsigned short* __restrict__ A,
        const unsigned short* __restrict__ B,
        const float* __restrict__ b_enc,
        unsigned short* __restrict__ Zh) {
    __shared__ __align__(128) char smemc[131072];   // 4 bufs x (A 16KB + B 16KB)
    int tid = threadIdx.x;
    int w = tid >> 6, l = tid & 63;
    int wm = w >> 2, wn = w & 3;            // 2 x 4 waves, wave tile 128x64
    int lm = l & 15, q = l >> 4;

    // bijective XCD swizzle (2048 % 8 == 0): each XCD owns an 8-col band of bn
    int orig = blockIdx.x;
    int swz = (orig & 7) * 256 + (orig >> 3);
    int bm = (swz & 255) >> 3;              // 0..31
    int bn = (swz >> 8) * 8 + (swz & 7);    // 0..63

    const unsigned short* gA = A + (size_t)bm * 256 * K_DIM;
    const unsigned short* gB = B + (size_t)bn * 256 * K_DIM;

    // staging: thread t loads unit (r0, t&3) [inst0] and (r0+128, t&3) [inst1];
    // pre-swizzled global k-unit = (t&3) ^ ((r0>>1)&3)
    int r0 = tid >> 2;
    int ul = (tid & 3) ^ ((tid >> 3) & 3);
    size_t off0 = (size_t)r0 * K_DIM + (size_t)ul * 8;
    size_t off1 = off0 + (size_t)128 * K_DIM;

    // fragment read byte offsets (within buffer); row&3-swizzle folds to lane const
    unsigned swzL = (unsigned)((q ^ ((lm >> 1) & 3)) * 16);
    unsigned aRowBase = (unsigned)((wm * 128 + lm) * 64) + swzL;
    unsigned bRowBase = (unsigned)((wn * 64 + lm) * 64) + swzL;

    f32x4 acc[8][4];
    #pragma unroll
    for (int i = 0; i < 8; i++)
        #pragma unroll
        for (int j = 0; j < 4; j++) acc[i][j] = (f32x4)0.0f;

    // prologue: stage tiles 0,1,2 (tile-ordered issue: 4 insts per tile)
    #pragma unroll
    for (int tt = 0; tt < 3; tt++) {
        char* db = smemc + tt * 32768 + tid * 16;
        async_copy16(gA + off0 + tt * 32, db);
        async_copy16(gB + off0 + tt * 32, db + 16384);
        async_copy16(gA + off1 + tt * 32, db + 8192);
        async_copy16(gB + off1 + tt * 32, db + 24576);
    }
    asm volatile("s_waitcnt vmcnt(8)" ::: "memory");   // tile 0 ready; 1,2 in flight
    __builtin_amdgcn_s_barrier();
    asm volatile("" ::: "memory");

    const unsigned short* sA0 = gA + off0 + 96;        // tile 3 sources
    const unsigned short* sA1 = gA + off1 + 96;
    const unsigned short* sB0 = gB + off0 + 96;
    const unsigned short* sB1 = gB + off1 + 96;

    // main loop: compute tile t (buf t&3), stage tile t+3 (buf (t+3)&3).
    // boundary: need tile t+1 complete -> leave tiles t+2,t+3 in flight = vmcnt(8)
    #pragma unroll 4
    for (int t = 0; t < 28; ++t) {
        unsigned bufOff = (unsigned)(t & 3) * 32768u;
        char* db = smemc + (unsigned)((t + 3) & 3) * 32768u + tid * 16;
        ktile256<true>(smemc, bufOff, aRowBase, bRowBase, acc, sA0, sA1, sB0, sB1, db);
        sA0 += 32; sA1 += 32; sB0 += 32; sB1 += 32;
        asm volatile("s_waitcnt vmcnt(8)" ::: "memory");
        __builtin_amdgcn_s_barrier();
        asm volatile("" ::: "memory");
    }
    {   // t = 28: stages tile 31 -> buf 3
        char* db = smemc + 3u * 32768u + tid * 16;
        ktile256<true>(smemc, 0u, aRowBase, bRowBase, acc, sA0, sA1, sB0, sB1, db);
        asm volatile("s_waitcnt vmcnt(8)" ::: "memory");
        __builtin_amdgcn_s_barrier();
        asm volatile("" ::: "memory");
    }
    // t = 29
    ktile256<false>(smemc, 1u * 32768u, aRowBase, bRowBase, acc, sA0, sA1, sB0, sB1, nullptr);
    asm volatile("s_waitcnt vmcnt(4)" ::: "memory");
    __builtin_amdgcn_s_barrier();
    asm volatile("" ::: "memory");
    // t = 30
    ktile256<false>(smemc, 2u * 32768u, aRowBase, bRowBase, acc, sA0, sA1, sB0, sB1, nullptr);
    asm volatile("s_waitcnt vmcnt(0)" ::: "memory");
    __builtin_amdgcn_s_barrier();
    asm volatile("" ::: "memory");
    // t = 31
    ktile256<false>(smemc, 3u * 32768u, aRowBase, bRowBase, acc, sA0, sA1, sB0, sB1, nullptr);

    // epilogue: bias + fp16 store (same mapping as verified kernel)
    size_t gm0 = (size_t)bm * 256 + wm * 128;
    size_t gn0 = (size_t)bn * 256 + wn * 64;
    #pragma unroll
    for (int ni = 0; ni < 4; ni++) {
        size_t gn = gn0 + ni * 16 + lm;
        float bv = b_enc[gn];
        #pragma unroll
        for (int mi = 0; mi < 8; mi++) {
            size_t gmb = gm0 + mi * 16 + q * 4;
            #pragma unroll
            for (int r = 0; r < 4; r++)
                Zh[(gmb + r) * N_LAT + gn] = f2h(acc[mi][ni][r] + bv);
        }
    }
}

// ---------------- K2 v3: register-held single-pass candidate select ----------------
// One block / row. 32 KB fp16 row held in registers (u16x8[8] per thread).
// Positive-only histogram (1024 linear bins, 4 copies) avoids the bin-0
// atomic flood; parallel suffix scan finds the 64th-value bucket.
__global__ __launch_bounds__(256) void select_cand(
        const unsigned short* __restrict__ Zh, int* __restrict__ cand, int* __restrict__ cnt) {
    __shared__ int hist[4][1024];
    __shared__ int wsum[4];
    __shared__ int s_above, s_bin, s_cn;
    __shared__ float s_cut;

    int r = blockIdx.x;
    int t = threadIdx.x;
    int w = t >> 6, l = t & 63;

    int* hp = &hist[0][0];
    #pragma unroll
    for (int i = 0; i < 16; i++) hp[t + i * 256] = 0;
    __syncthreads();

    const u32x4* zg = (const u32x4*)(Zh + (size_t)r * N_LAT);
    u16x8 v[8];
    #pragma unroll
    for (int it = 0; it < 8; it++) {
        u32x4 raw = __builtin_nontemporal_load(&zg[t + it * 256]);
        u16x8 vv;
        __builtin_memcpy(&vv, &raw, 16);
        v[it] = vv;
        #pragma unroll
        for (int j = 0; j < 8; j++) {
            float f = h2f(vv[j]);
            if (f > 0.0f) {
                int b = min((int)(f * 64.0f), 1023);
                atomicAdd(&hist[w][b], 1);
            }
        }
    }
    __syncthreads();

    // merge 4 copies; thread t owns bins 4t..4t+3; g = group sum
    int g = 0;
    #pragma unroll
    for (int i = 0; i < 4; i++) {
        int b = 4 * t + i;
        int m = hist[0][b] + hist[1][b] + hist[2][b] + hist[3][b];
        hist[0][b] = m;
        g += m;
    }

    // block-wide inclusive prefix of g (low->high)
    int val = g;
    #pragma unroll
    for (int d = 1; d < 64; d <<= 1) {
        int n = __shfl_up(val, d, 64);
        if (l >= d) val += n;
    }
    if (l == 63) wsum[w] = val;
    __syncthreads();
    int off = 0;
    for (int i = 0; i < w; i++) off += wsum[i];
    int total = wsum[0] + wsum[1] + wsum[2] + wsum[3];
    int incl = val + off;
    int above = total - incl;                      // strictly above this thread's group
    if (above < TOPK && above + g >= TOPK) {       // exactly one thread
        s_above = above;
        s_bin = t;
    }
    __syncthreads();
    if (t == 0) {
        int c = s_above;
        int b = s_bin * 4 + 3;
        for (; b > s_bin * 4; b--) {
            if (c + hist[0][b] >= TOPK) break;
            c += hist[0][b];
        }
        s_cut = (float)b * (1.0f / 64.0f) - MARGIN;
        s_cn = 0;
    }
    __syncthreads();

    float cut = s_cut;
    #pragma unroll
    for (int it = 0; it < 8; it++) {
        #pragma unroll
        for (int j = 0; j < 8; j++) {
            float f = h2f(v[it][j]);
            if (f >= cut) {
                int p = atomicAdd(&s_cn, 1);
                if (p < CAND_CAP) cand[(size_t)r * CAND_CAP + p] = (t + it * 256) * 8 + j;
            }
        }
    }
    __syncthreads();
    if (t == 0) cnt[r] = min(s_cn, CAND_CAP);
}

// ---------------- K3: exact fp64 recompute + true top-64 (float4 gathers) ----------------
__global__ void exact_topk(const float* __restrict__ x, const float* __restrict__ W,
                           const float* __restrict__ b_enc,
                           const int* __restrict__ cand, const int* __restrict__ cnt,
                           int* __restrict__ seli, float* __restrict__ selv) {
    int r = blockIdx.x;
    __shared__ float xs[K_DIM];
    __shared__ double vals[CAND_CAP];
    __shared__ int ns[CAND_CAP];
    int t = threadIdx.x;
    ((float4*)xs)[t] = ((const float4*)(x + (size_t)r * K_DIM))[t];
    int n_c = cnt[r];
    if (t < n_c) ns[t] = cand[(size_t)r * CAND_CAP + t];
    __syncthreads();

    int w = t >> 6, l = t & 63;
    for (int c = w; c < n_c; c += 4) {
        const float4* wr = (const float4*)(W + (size_t)ns[c] * K_DIM);
        double s = 0.0;
        #pragma unroll
        for (int i = 0; i < 4; i++) {
            float4 wv = wr[l + i * 64];
            float4 xv = ((const float4*)xs)[l + i * 64];
            s += (double)xv.x * wv.x + (double)xv.y * wv.y
               + (double)xv.z * wv.z + (double)xv.w * wv.w;
        }
        for (int o = 32; o > 0; o >>= 1) s += __shfl_down(s, o, 64);
        if (l == 0) vals[c] = s + (double)b_enc[ns[c]];
    }
    __syncthreads();

    if (t < n_c) {
        double v = vals[t];
        int n = ns[t];
        int rank = 0;
        for (int j = 0; j < n_c; j++) {
            double vj = vals[j];
            if (vj > v || (vj == v && ns[j] < n)) rank++;   // lax.top_k tie-break
        }
        if (rank < TOPK) {
            seli[(size_t)r * TOPK + rank] = n;
            selv[(size_t)r * TOPK + rank] = (float)(v > 0.0 ? v : 0.0);
        }
    }
}

// ---------------- K4: fused zero-z + scatter + sparse decoder ----------------
__global__ void decode(const int* __restrict__ seli, const float* __restrict__ selv,
                       const unsigned short* __restrict__ WdT,
                       const float* __restrict__ b_dec,
                       float* __restrict__ recon, float* __restrict__ Z) {
    int r = blockIdx.x;
    __shared__ int is[TOPK];
    __shared__ float vs[TOPK];
    int t = threadIdx.x;
    if (t < TOPK) {
        is[t] = seli[(size_t)r * TOPK + t];
        vs[t] = selv[(size_t)r * TOPK + t];
    }
    // zero this row's z (streaming stores)
    f32x4* zr4 = (f32x4*)(Z + (size_t)r * N_LAT);
    f32x4 z4 = (f32x4)0.0f;
    #pragma unroll
    for (int it = 0; it < 16; it++)
        __builtin_nontemporal_store(z4, &zr4[t + it * 256]);
    __syncthreads();
    if (t < TOPK) Z[(size_t)r * N_LAT + is[t]] = vs[t];

    f32x4 acc = (f32x4)0.0f;
    #pragma unroll 4
    for (int j = 0; j < TOPK; j++) {
        const unsigned short* wr = WdT + (size_t)is[j] * K_DIM;
        float v = vs[j];
        ushort4 w4 = *(const ushort4*)(wr + 4 * t);
        acc.x += v * bf2f(w4.x);
        acc.y += v * bf2f(w4.y);
        acc.z += v * bf2f(w4.z);
        acc.w += v * bf2f(w4.w);
    }
    f32x4 bd = *(const f32x4*)(b_dec + 4 * t);
    acc += bd;
    __builtin_nontemporal_store(acc, (f32x4*)(recon + (size_t)r * K_DIM + 4 * t));
}

// ---------------- launch ----------------
extern "C" void kernel_launch(void* const* d_in, const int* in_sizes, int n_in,
                              void* d_out, int out_size, void* d_ws, size_t ws_size,
                              hipStream_t stream) {
    const float* x     = (const float*)d_in[0];
    const float* W_enc = (const float*)d_in[1];
    const float* b_enc = (const float*)d_in[2];
    const float* W_dec = (const float*)d_in[3];
    const float* b_dec = (const float*)d_in[4];
    float* recon = (float*)d_out;
    float* Z     = recon + (size_t)M_BATCH * K_DIM;     // fp32 z output region
    unsigned short* Zh = (unsigned short*)Z;            // fp16 scratch inside z region

    char* ws = (char*)d_ws;
    unsigned short* Wh  = (unsigned short*)(ws);                 // 33,554,432 B
    unsigned short* xh  = (unsigned short*)(ws + 33554432);      // 16,777,216 B
    unsigned short* WdT = (unsigned short*)(ws + 50331648);      // 33,554,432 B
    int*   cand = (int*)  (ws + 83886080);                       //  8,388,608 B
    int*   cnt  = (int*)  (ws + 92274688);                       //     32,768 B
    int*   seli = (int*)  (ws + 92307456);                       //  2,097,152 B
    float* selv = (float*)(ws + 94404608);                       //  2,097,152 B

    to_bf16<<<(N_LAT * K_DIM / 4 + 255) / 256, 256, 0, stream>>>(
        (const float4*)W_enc, Wh, N_LAT * K_DIM / 4);
    to_bf16<<<(M_BATCH * K_DIM / 4 + 255) / 256, 256, 0, stream>>>(
        (const float4*)x, xh, M_BATCH * K_DIM / 4);
    transpose_wdec<<<dim3(N_LAT / 64, K_DIM / 64), 256, 0, stream>>>(W_dec, WdT);

    enc_gemm256<<<(M_BATCH / 256) * (N_LAT / 256), 512, 0, stream>>>(xh, Wh, b_enc, Zh);

    select_cand<<<M_BATCH, 256, 0, stream>>>(Zh, cand, cnt);

    exact_topk<<<M_BATCH, 256, 0, stream>>>(x, W_enc, b_enc, cand, cnt, seli, selv);

    decode<<<M_BATCH, 256, 0, stream>>>(seli, selv, WdT, b_dec, recon, Z);
}

// Round 3
// 1470.230 us; speedup vs baseline: 1.0116x; 1.0116x over previous
//
#include <hip/hip_runtime.h>
#include <stdint.h>

// TopK SAE forward, MI355X/gfx950.
// bf16-MFMA approximate encoder (fp16 Z scratch) -> fused per-row kernel:
// ballot binary-search candidate select (bit-identical to 1024-bin histogram,
// margin 0.015) -> exact fp64 recompute of ~77 candidates/row -> true top-64
// (index tie-break) -> zero+scatter+sparse-decode with bf16 W_decT.
//
// R1: enc_gemm 256x256-tile, BK=32, 8-wave pipeline (quad-buffered LDS,
//     counted vmcnt(8), XOR-swizzle via pre-swizzled global source, setprio,
//     XCD swizzle).
// R2: select+exact+decode fused into one per-row kernel; histogram replaced
//     by ballot binary search (no LDS atomics).
// R3 FIX: R2 raced — Zh was packed at 32KB/row inside the Z region, so block
//     r's Z-row zeroing wiped Zh rows 2r,2r+1 before those blocks read them.
//     Zh now lives in the FIRST HALF of Z row r's own 64KB slot (stride
//     2*N_LAT halves): block r only ever clobbers the Zh row it already holds
//     in registers. No cross-block aliasing remains.

#define M_BATCH 8192
#define K_DIM   1024
#define N_LAT   16384
#define ZH_STRIDE (2 * N_LAT)   // halves per Zh row (row-local aliasing with Z)
#define TOPK    64
#define CAND_CAP 256
#define MARGIN  0.015f

typedef float f32x4 __attribute__((ext_vector_type(4)));
typedef unsigned int u32x4 __attribute__((ext_vector_type(4)));
typedef short s16x8 __attribute__((ext_vector_type(8)));
typedef unsigned short u16x8 __attribute__((ext_vector_type(8)));

typedef __attribute__((address_space(3))) void       lds_void;
typedef const __attribute__((address_space(1))) void glb_void;

__device__ __forceinline__ void async_copy16(const void* g, void* l) {
    __builtin_amdgcn_global_load_lds((glb_void*)g, (lds_void*)l, 16, 0, 0);
}

__device__ __forceinline__ unsigned short f2bf(float f) {
    uint32_t u = __float_as_uint(f);
    uint32_t r = (u + 0x7FFFu + ((u >> 16) & 1u)) >> 16;   // RNE
    return (unsigned short)r;
}
__device__ __forceinline__ float bf2f(unsigned short h) {
    return __uint_as_float(((uint32_t)h) << 16);
}
__device__ __forceinline__ unsigned short f2h(float f) {
    _Float16 h = (_Float16)f;
    unsigned short u;
    __builtin_memcpy(&u, &h, 2);
    return u;
}
__device__ __forceinline__ float h2f(unsigned short u) {
    _Float16 h;
    __builtin_memcpy(&h, &u, 2);
    return (float)h;
}

// ---------------- K0a: fp32 -> bf16 conversion ----------------
__global__ void to_bf16(const float4* __restrict__ src, unsigned short* __restrict__ dst,
                        int nvec) {
    int i = blockIdx.x * blockDim.x + threadIdx.x;
    if (i < nvec) {
        float4 f = src[i];
        ushort4 o;
        o.x = f2bf(f.x); o.y = f2bf(f.y); o.z = f2bf(f.z); o.w = f2bf(f.w);
        *(ushort4*)(dst + (size_t)i * 4) = o;
    }
}

// ---------------- K0b: W_dec [1024,16384] fp32 -> W_decT [16384,1024] bf16 ----------------
__global__ void transpose_wdec(const float* __restrict__ Wd, unsigned short* __restrict__ WdT) {
    __shared__ float tile[64][65];
    int bj = blockIdx.x;
    int bi = blockIdx.y;
    int t = threadIdx.x;
    int tj = t & 63, ti4 = t >> 6;
    #pragma unroll
    for (int rr = 0; rr < 16; rr++) {
        int i = ti4 * 16 + rr;
        tile[i][tj] = Wd[(size_t)(bi * 64 + i) * N_LAT + bj * 64 + tj];
    }
    __syncthreads();
    int ti = t & 63, tj4 = t >> 6;
    #pragma unroll
    for (int rr = 0; rr < 16; rr++) {
        int j = tj4 * 16 + rr;
        WdT[(size_t)(bj * 64 + j) * K_DIM + bi * 64 + ti] = f2bf(tile[ti][j]);
    }
}

// ---------------- K1: bf16 MFMA encoder GEMM, 256x256 tile, pipelined ----------------
// LDS buffer layout (per 32KB buffer): A [256 rows][4 units of 16B], then B same
// at +16384. Unit u of row r stored at u ^ ((r>>1)&3)  (involution; applied by
// pre-swizzling the global source; global_load_lds dest stays linear).
template<bool STAGE>
__device__ __forceinline__ void ktile256(
        const char* smemc, unsigned bufOff,
        unsigned aRowBase, unsigned bRowBase,
        f32x4 (&acc)[8][4],
        const unsigned short* sA0, const unsigned short* sA1,
        const unsigned short* sB0, const unsigned short* sB1,
        char* db)
{
    const char* bufA = smemc + bufOff;
    const char* bufB = bufA + 16384;
    if constexpr (STAGE) {
        async_copy16(sA0, db);
        async_copy16(sB0, db + 16384);
    }
    s16x8 bfr[4], afr[4];
    #pragma unroll
    for (int ni = 0; ni < 4; ni++)
        bfr[ni] = *(const s16x8*)(bufB + bRowBase + ni * 1024);
    #pragma unroll
    for (int mi = 0; mi < 4; mi++)
        afr[mi] = *(const s16x8*)(bufA + aRowBase + mi * 1024);
    __builtin_amdgcn_s_setprio(1);
    #pragma unroll
    for (int mi = 0; mi < 4; mi++)
        #pragma unroll
        for (int ni = 0; ni < 4; ni++)
            acc[mi][ni] = __builtin_amdgcn_mfma_f32_16x16x32_bf16(
                afr[mi], bfr[ni], acc[mi][ni], 0, 0, 0);
    __builtin_amdgcn_s_setprio(0);
    if constexpr (STAGE) {
        async_copy16(sA1, db + 8192);
        async_copy16(sB1, db + 24576);
    }
    #pragma unroll
    for (int mi = 0; mi < 4; mi++)
        afr[mi] = *(const s16x8*)(bufA + aRowBase + (4 + mi) * 1024);
    __builtin_amdgcn_s_setprio(1);
    #pragma unroll
    for (int mi = 0; mi < 4; mi++)
        #pragma unroll
        for (int ni = 0; ni < 4; ni++)
            acc[4 + mi][ni] = __builtin_amdgcn_mfma_f32_16x16x32_bf16(
                afr[mi], bfr[ni], acc[4 + mi][ni], 0, 0, 0);
    __builtin_amdgcn_s_setprio(0);
}

__global__ __launch_bounds__(512, 2) void enc_gemm256(
        const unsigned short* __restrict__ A,
        const unsigned short* __restrict__ B,
        const float* __restrict__ b_enc,
        unsigned short* __restrict__ Zh) {
    __shared__ __align__(128) char smemc[131072];   // 4 bufs x (A 16KB + B 16KB)
    int tid = threadIdx.x;
    int w = tid >> 6, l = tid & 63;
    int wm = w >> 2, wn = w & 3;            // 2 x 4 waves, wave tile 128x64
    int lm = l & 15, q = l >> 4;

    // bijective XCD swizzle (2048 % 8 == 0): each XCD owns an 8-col band of bn
    int orig = blockIdx.x;
    int swz = (orig & 7) * 256 + (orig >> 3);
    int bm = (swz & 255) >> 3;              // 0..31
    int bn = (swz >> 8) * 8 + (swz & 7);    // 0..63

    const unsigned short* gA = A + (size_t)bm * 256 * K_DIM;
    const unsigned short* gB = B + (size_t)bn * 256 * K_DIM;

    // staging: thread t loads unit (r0, t&3) [inst0] and (r0+128, t&3) [inst1];
    // pre-swizzled global k-unit = (t&3) ^ ((r0>>1)&3)
    int r0 = tid >> 2;
    int ul = (tid & 3) ^ ((tid >> 3) & 3);
    size_t off0 = (size_t)r0 * K_DIM + (size_t)ul * 8;
    size_t off1 = off0 + (size_t)128 * K_DIM;

    // fragment read byte offsets (within buffer); row&3-swizzle folds to lane const
    unsigned swzL = (unsigned)((q ^ ((lm >> 1) & 3)) * 16);
    unsigned aRowBase = (unsigned)((wm * 128 + lm) * 64) + swzL;
    unsigned bRowBase = (unsigned)((wn * 64 + lm) * 64) + swzL;

    f32x4 acc[8][4];
    #pragma unroll
    for (int i = 0; i < 8; i++)
        #pragma unroll
        for (int j = 0; j < 4; j++) acc[i][j] = (f32x4)0.0f;

    // prologue: stage tiles 0,1,2 (tile-ordered issue: 4 insts per tile)
    #pragma unroll
    for (int tt = 0; tt < 3; tt++) {
        char* db = smemc + tt * 32768 + tid * 16;
        async_copy16(gA + off0 + tt * 32, db);
        async_copy16(gB + off0 + tt * 32, db + 16384);
        async_copy16(gA + off1 + tt * 32, db + 8192);
        async_copy16(gB + off1 + tt * 32, db + 24576);
    }
    asm volatile("s_waitcnt vmcnt(8)" ::: "memory");   // tile 0 ready; 1,2 in flight
    __builtin_amdgcn_s_barrier();
    asm volatile("" ::: "memory");

    const unsigned short* sA0 = gA + off0 + 96;        // tile 3 sources
    const unsigned short* sA1 = gA + off1 + 96;
    const unsigned short* sB0 = gB + off0 + 96;
    const unsigned short* sB1 = gB + off1 + 96;

    // main loop: compute tile t (buf t&3), stage tile t+3 (buf (t+3)&3).
    // boundary: need tile t+1 complete -> leave tiles t+2,t+3 in flight = vmcnt(8)
    #pragma unroll 4
    for (int t = 0; t < 28; ++t) {
        unsigned bufOff = (unsigned)(t & 3) * 32768u;
        char* db = smemc + (unsigned)((t + 3) & 3) * 32768u + tid * 16;
        ktile256<true>(smemc, bufOff, aRowBase, bRowBase, acc, sA0, sA1, sB0, sB1, db);
        sA0 += 32; sA1 += 32; sB0 += 32; sB1 += 32;
        asm volatile("s_waitcnt vmcnt(8)" ::: "memory");
        __builtin_amdgcn_s_barrier();
        asm volatile("" ::: "memory");
    }
    {   // t = 28: stages tile 31 -> buf 3
        char* db = smemc + 3u * 32768u + tid * 16;
        ktile256<true>(smemc, 0u, aRowBase, bRowBase, acc, sA0, sA1, sB0, sB1, db);
        asm volatile("s_waitcnt vmcnt(8)" ::: "memory");
        __builtin_amdgcn_s_barrier();
        asm volatile("" ::: "memory");
    }
    // t = 29
    ktile256<false>(smemc, 1u * 32768u, aRowBase, bRowBase, acc, sA0, sA1, sB0, sB1, nullptr);
    asm volatile("s_waitcnt vmcnt(4)" ::: "memory");
    __builtin_amdgcn_s_barrier();
    asm volatile("" ::: "memory");
    // t = 30
    ktile256<false>(smemc, 2u * 32768u, aRowBase, bRowBase, acc, sA0, sA1, sB0, sB1, nullptr);
    asm volatile("s_waitcnt vmcnt(0)" ::: "memory");
    __builtin_amdgcn_s_barrier();
    asm volatile("" ::: "memory");
    // t = 31
    ktile256<false>(smemc, 3u * 32768u, aRowBase, bRowBase, acc, sA0, sA1, sB0, sB1, nullptr);

    // epilogue: bias + fp16 store (row stride ZH_STRIDE halves: Zh row r lives
    // in the first half of Z row r's 64KB slot — row-local aliasing only)
    size_t gm0 = (size_t)bm * 256 + wm * 128;
    size_t gn0 = (size_t)bn * 256 + wn * 64;
    #pragma unroll
    for (int ni = 0; ni < 4; ni++) {
        size_t gn = gn0 + ni * 16 + lm;
        float bv = b_enc[gn];
        #pragma unroll
        for (int mi = 0; mi < 8; mi++) {
            size_t gmb = gm0 + mi * 16 + q * 4;
            #pragma unroll
            for (int r = 0; r < 4; r++)
                Zh[(gmb + r) * (size_t)ZH_STRIDE + gn] = f2h(acc[mi][ni][r] + bv);
        }
    }
}

// ---------------- K2: fused select (ballot binary search) + exact fp64 topk
//                       + zero/scatter/decode, one block per row ----------------
// Cut semantics are bit-identical to the old 1024-bin histogram:
//   b = max{ j in [0,1023] : count(f >= j/64) >= 64 },  cut = b/64 - MARGIN.
// Probe thresholds j/64 are exactly representable in fp16, so fp16 compares
// reproduce the f32 histogram binning exactly.
__global__ __launch_bounds__(256) void fused_sel_dec(
        const unsigned short* __restrict__ Zh,
        const float* __restrict__ x, const float* __restrict__ W,
        const float* __restrict__ b_enc,
        const unsigned short* __restrict__ WdT,
        const float* __restrict__ b_dec,
        float* __restrict__ recon, float* __restrict__ Z) {
    __shared__ float xs[K_DIM];
    __shared__ double vals[CAND_CAP];
    __shared__ int ns[CAND_CAP];
    __shared__ int is[TOPK];
    __shared__ float vs[TOPK];
    __shared__ int wred[10][4];
    __shared__ int s_cn;

    int r = blockIdx.x;
    int t = threadIdx.x;
    int w = t >> 6, l = t & 63;

    // x row -> LDS (consumed by exact phase)
    ((float4*)xs)[t] = ((const float4*)(x + (size_t)r * K_DIM))[t];
    if (t == 0) s_cn = 0;

    // Zh row -> registers (32 KB / block, 128 B / thread); row-local slot,
    // so the later Z-row zeroing only clobbers data this block already holds.
    const u32x4* zg = (const u32x4*)(Zh + (size_t)r * ZH_STRIDE);
    u16x8 v[8];
    #pragma unroll
    for (int it = 0; it < 8; it++) {
        u32x4 raw = __builtin_nontemporal_load(&zg[t + it * 256]);
        __builtin_memcpy(&v[it], &raw, 16);
    }

    // 10-step binary search: no atomics, count via v_cmp_ge_f16 + ballot popcount
    int lo = 0, hi = 1023;
    #pragma unroll
    for (int iter = 0; iter < 10; iter++) {
        int mid = (lo + hi + 1) >> 1;
        _Float16 T = (_Float16)((float)mid * (1.0f / 64.0f));
        int c = 0;
        #pragma unroll
        for (int it = 0; it < 8; it++)
            #pragma unroll
            for (int j = 0; j < 8; j++) {
                _Float16 h;
                unsigned short u = v[it][j];
                __builtin_memcpy(&h, &u, 2);
                c += (int)__popcll(__ballot(h >= T));
            }
        if (l == 0) wred[iter][w] = c;
        __syncthreads();
        int tot = wred[iter][0] + wred[iter][1] + wred[iter][2] + wred[iter][3];
        if (tot >= TOPK) lo = mid; else hi = mid - 1;
    }
    float cut = (float)lo * (1.0f / 64.0f) - MARGIN;

    // candidate collection (~77/row, capped at 256)
    #pragma unroll
    for (int it = 0; it < 8; it++)
        #pragma unroll
        for (int j = 0; j < 8; j++) {
            float f = h2f(v[it][j]);
            if (f >= cut) {
                int p = atomicAdd(&s_cn, 1);
                if (p < CAND_CAP) ns[p] = (t + it * 256) * 8 + j;
            }
        }
    __syncthreads();
    int n_c = min(s_cn, CAND_CAP);

    // exact fp64 recompute of candidates
    for (int c = w; c < n_c; c += 4) {
        const float4* wr = (const float4*)(W + (size_t)ns[c] * K_DIM);
        double s = 0.0;
        #pragma unroll
        for (int i = 0; i < 4; i++) {
            float4 wv = wr[l + i * 64];
            float4 xv = ((const float4*)xs)[l + i * 64];
            s += (double)xv.x * wv.x + (double)xv.y * wv.y
               + (double)xv.z * wv.z + (double)xv.w * wv.w;
        }
        for (int o = 32; o > 0; o >>= 1) s += __shfl_down(s, o, 64);
        if (l == 0) vals[c] = s + (double)b_enc[ns[c]];
    }
    __syncthreads();

    // rank (lax.top_k tie-break: value desc, index asc)
    if (t < n_c) {
        double vv = vals[t];
        int n = ns[t];
        int rank = 0;
        for (int j = 0; j < n_c; j++) {
            double vj = vals[j];
            if (vj > vv || (vj == vv && ns[j] < n)) rank++;
        }
        if (rank < TOPK) {
            is[rank] = n;
            vs[rank] = (float)(vv > 0.0 ? vv : 0.0);
        }
    }
    __syncthreads();

    // zero this row's z (streaming stores), then scatter.
    // This overwrites this row's own Zh slot only (already in registers).
    f32x4* zr4 = (f32x4*)(Z + (size_t)r * N_LAT);
    f32x4 z4 = (f32x4)0.0f;
    #pragma unroll
    for (int it = 0; it < 16; it++)
        __builtin_nontemporal_store(z4, &zr4[t + it * 256]);
    __syncthreads();
    if (t < TOPK) Z[(size_t)r * N_LAT + is[t]] = vs[t];

    // sparse decode
    f32x4 acc = (f32x4)0.0f;
    #pragma unroll 4
    for (int j = 0; j < TOPK; j++) {
        const unsigned short* wr = WdT + (size_t)is[j] * K_DIM;
        float vj = vs[j];
        ushort4 w4 = *(const ushort4*)(wr + 4 * t);
        acc.x += vj * bf2f(w4.x);
        acc.y += vj * bf2f(w4.y);
        acc.z += vj * bf2f(w4.z);
        acc.w += vj * bf2f(w4.w);
    }
    f32x4 bd = *(const f32x4*)(b_dec + 4 * t);
    acc += bd;
    __builtin_nontemporal_store(acc, (f32x4*)(recon + (size_t)r * K_DIM + 4 * t));
}

// ---------------- launch ----------------
extern "C" void kernel_launch(void* const* d_in, const int* in_sizes, int n_in,
                              void* d_out, int out_size, void* d_ws, size_t ws_size,
                              hipStream_t stream) {
    const float* x     = (const float*)d_in[0];
    const float* W_enc = (const float*)d_in[1];
    const float* b_enc = (const float*)d_in[2];
    const float* W_dec = (const float*)d_in[3];
    const float* b_dec = (const float*)d_in[4];
    float* recon = (float*)d_out;
    float* Z     = recon + (size_t)M_BATCH * K_DIM;     // fp32 z output region
    unsigned short* Zh = (unsigned short*)Z;            // fp16 scratch, row r at
                                                        // halves offset r*ZH_STRIDE

    char* ws = (char*)d_ws;
    unsigned short* Wh  = (unsigned short*)(ws);                 // 33,554,432 B
    unsigned short* xh  = (unsigned short*)(ws + 33554432);      // 16,777,216 B
    unsigned short* WdT = (unsigned short*)(ws + 50331648);      // 33,554,432 B

    to_bf16<<<(N_LAT * K_DIM / 4 + 255) / 256, 256, 0, stream>>>(
        (const float4*)W_enc, Wh, N_LAT * K_DIM / 4);
    to_bf16<<<(M_BATCH * K_DIM / 4 + 255) / 256, 256, 0, stream>>>(
        (const float4*)x, xh, M_BATCH * K_DIM / 4);
    transpose_wdec<<<dim3(N_LAT / 64, K_DIM / 64), 256, 0, stream>>>(W_dec, WdT);

    enc_gemm256<<<(M_BATCH / 256) * (N_LAT / 256), 512, 0, stream>>>(xh, Wh, b_enc, Zh);

    fused_sel_dec<<<M_BATCH, 256, 0, stream>>>(Zh, x, W_enc, b_enc, WdT, b_dec, recon, Z);
}